// Round 1
// baseline (561.213 us; speedup 1.0000x reference)
//
#include <hip/hip_runtime.h>
#include <math.h>

#define N_NODES    50000
#define N_EDGES_IN 800000
#define N_EDGES    850000   // + self loops
#define N_GRAPHS   512
#define NEG_SLOPE  0.2f
#define EPS_F      1e-16f

// ---------------- embedding gather: x[n] = emb[ids[n]] ----------------
__global__ void k_gather(const int* __restrict__ ids, const float4* __restrict__ emb,
                         float4* __restrict__ x) {
    int tid = blockIdx.x * blockDim.x + threadIdx.x;   // N_NODES * 32
    if (tid >= N_NODES * 32) return;
    int n = tid >> 5, c = tid & 31;
    x[n * 32 + c] = emb[ids[n] * 32 + c];
}

// ---------------- GEMM: h[N,128] = x[N,128] @ W[128,128] (fp32, vector ALU) --
// block = 256 threads, 64 rows per block, full 128 cols.
// thread t: rows (t>>5)*8 .. +7, cols (t&31)*4 .. +3  (8x4 accumulator)
__global__ __launch_bounds__(256) void k_gemm(const float* __restrict__ x,
                                              const float* __restrict__ W,
                                              float* __restrict__ h) {
    __shared__ float Ws[64 * 128];   // 32 KB  (one K-half)
    __shared__ float Xs[64 * 64];    // 16 KB
    int t = threadIdx.x;
    int row0 = blockIdx.x * 64;
    int g  = t >> 5;          // 0..7 row group
    int c4 = (t & 31) * 4;    // col start
    float acc[8][4] = {};
    for (int kc = 0; kc < 2; kc++) {
        // stage W rows [kc*64, kc*64+64) x 128  (2048 float4, 8/thread)
        {
            const float4* Wg = (const float4*)(W + kc * 64 * 128);
            float4* Wsv = (float4*)Ws;
            #pragma unroll
            for (int i = 0; i < 8; i++) Wsv[t + i * 256] = Wg[t + i * 256];
        }
        // stage X rows [row0, row0+64) cols [kc*64, +64)  (1024 float4, 4/thread)
        {
            float4* Xsv = (float4*)Xs;
            #pragma unroll
            for (int i = 0; i < 4; i++) {
                int j = t + i * 256;
                int r = j >> 4, cf = j & 15;
                int gr = row0 + r; if (gr >= N_NODES) gr = N_NODES - 1;
                Xsv[j] = ((const float4*)(x + (size_t)gr * 128 + kc * 64))[cf];
            }
        }
        __syncthreads();
        #pragma unroll 4
        for (int k = 0; k < 64; k++) {
            float4 wv = *(const float4*)&Ws[k * 128 + c4];
            #pragma unroll
            for (int i = 0; i < 8; i++) {
                float xv = Xs[(g * 8 + i) * 64 + k];
                acc[i][0] += xv * wv.x;
                acc[i][1] += xv * wv.y;
                acc[i][2] += xv * wv.z;
                acc[i][3] += xv * wv.w;
            }
        }
        __syncthreads();
    }
    #pragma unroll
    for (int i = 0; i < 8; i++) {
        int r = row0 + g * 8 + i;
        if (r < N_NODES)
            *(float4*)&h[(size_t)r * 128 + c4] =
                make_float4(acc[i][0], acc[i][1], acc[i][2], acc[i][3]);
    }
}

// ---------------- per-node attention scores: as_[n]=h[n]·a_src, ad_[n]=h[n]·a_dst
__global__ void k_scores(const float2* __restrict__ h2, const float2* __restrict__ av_s,
                         const float2* __restrict__ av_d,
                         float* __restrict__ as_, float* __restrict__ ad_) {
    int n = (blockIdx.x * blockDim.x + threadIdx.x) >> 6;
    int lane = threadIdx.x & 63;
    if (n >= N_NODES) return;
    float2 hv = h2[(size_t)n * 64 + lane];
    float2 sa = av_s[lane], da = av_d[lane];
    float ps = hv.x * sa.x + hv.y * sa.y;
    float pd = hv.x * da.x + hv.y * da.y;
    #pragma unroll
    for (int off = 32; off; off >>= 1) {
        ps += __shfl_xor(ps, off, 64);
        pd += __shfl_xor(pd, off, 64);
    }
    if (lane == 0) { as_[n] = ps; ad_[n] = pd; }
}

// ---------------- CSR build by dst ----------------
__global__ void k_hist(const int* __restrict__ ei, int* __restrict__ counts) {
    int e = blockIdx.x * blockDim.x + threadIdx.x;
    if (e >= N_EDGES) return;
    int d = (e < N_EDGES_IN) ? ei[N_EDGES_IN + e] : (e - N_EDGES_IN);
    atomicAdd(&counts[d], 1);
}

__global__ void k_scan1(const int* __restrict__ counts, int* __restrict__ row_ptr,
                        int* __restrict__ blksum) {
    __shared__ int s[256];
    int t = threadIdx.x, i = blockIdx.x * 256 + t;
    int v = (i < N_NODES) ? counts[i] : 0;
    s[t] = v; __syncthreads();
    for (int off = 1; off < 256; off <<= 1) {
        int x = (t >= off) ? s[t - off] : 0;
        __syncthreads(); s[t] += x; __syncthreads();
    }
    if (i < N_NODES) row_ptr[i] = s[t] - v;           // block-local exclusive
    if (t == 255) blksum[blockIdx.x] = s[255];
}

__global__ void k_scan2(int* __restrict__ blksum, int* __restrict__ row_ptr, int nb) {
    __shared__ int s[256];
    int t = threadIdx.x;
    int v = (t < nb) ? blksum[t] : 0;
    s[t] = v; __syncthreads();
    for (int off = 1; off < 256; off <<= 1) {
        int x = (t >= off) ? s[t - off] : 0;
        __syncthreads(); s[t] += x; __syncthreads();
    }
    if (t < nb) blksum[t] = s[t] - v;                 // exclusive block offsets
    if (t == 0) row_ptr[N_NODES] = N_EDGES;           // total is a compile-time constant
}

__global__ void k_scan3(int* __restrict__ row_ptr, const int* __restrict__ blksum) {
    int i = blockIdx.x * 256 + threadIdx.x;
    if (i < N_NODES) row_ptr[i] += blksum[blockIdx.x];
}

__global__ void k_scatter(const int* __restrict__ ei, const int* __restrict__ row_ptr,
                          int* __restrict__ fill, int* __restrict__ srcs) {
    int e = blockIdx.x * blockDim.x + threadIdx.x;
    if (e >= N_EDGES) return;
    int s, d;
    if (e < N_EDGES_IN) { s = ei[e]; d = ei[N_EDGES_IN + e]; }
    else                { s = e - N_EDGES_IN; d = s; }
    int pos = row_ptr[d] + atomicAdd(&fill[d], 1);
    srcs[pos] = s;
}

// ---------------- softmax + weighted aggregation, one wave per dst ----------
// lane owns output dims {2*lane, 2*lane+1}; zero atomics, coalesced h-row reads.
__global__ __launch_bounds__(256) void k_aggregate(
        const float2* __restrict__ h2, const float* __restrict__ as_,
        const float* __restrict__ ad_, const int* __restrict__ row_ptr,
        const int* __restrict__ srcs, const float2* __restrict__ bias2,
        float2* __restrict__ xout, int do_relu) {
    int d = (blockIdx.x * blockDim.x + threadIdx.x) >> 6;
    int lane = threadIdx.x & 63;
    if (d >= N_NODES) return;
    int lo = row_ptr[d], hi = row_ptr[d + 1];
    int deg = hi - lo;                     // >= 1 (self-loop)
    float add = ad_[d];

    // pass A: online softmax stats per lane, then wave merge
    float m_l = -1e30f, s_l = 0.f;
    for (int j0 = 0; j0 < deg; j0 += 64) {
        int j = j0 + lane;
        if (j < deg) {
            int sidx = srcs[lo + j];
            float e = as_[sidx] + add;
            e = (e > 0.f) ? e : NEG_SLOPE * e;
            float nm = fmaxf(m_l, e);
            s_l = s_l * __expf(m_l - nm) + __expf(e - nm);
            m_l = nm;
        }
    }
    float m = m_l, s = s_l;
    #pragma unroll
    for (int off = 32; off; off >>= 1) {
        float om = __shfl_xor(m, off, 64);
        float os = __shfl_xor(s, off, 64);
        float nm = fmaxf(m, om);            // finite-sentinel: no inf-inf NaN
        s = s * __expf(m - nm) + os * __expf(om - nm);
        m = nm;
    }
    float inv = 1.f / (s + EPS_F);

    // pass B: accumulate alpha * h[src]; weights broadcast via shuffles
    float2 acc = make_float2(0.f, 0.f);
    for (int j0 = 0; j0 < deg; j0 += 64) {
        int j = j0 + lane;
        int sidx = 0; float w = 0.f;
        if (j < deg) {
            sidx = srcs[lo + j];
            float e = as_[sidx] + add;
            e = (e > 0.f) ? e : NEG_SLOPE * e;
            w = __expf(e - m) * inv;
        }
        int cnt = min(64, deg - j0);
        for (int jj = 0; jj < cnt; jj++) {
            float wj = __shfl(w, jj, 64);
            int   sj = __shfl(sidx, jj, 64);
            float2 hv = h2[(size_t)sj * 64 + lane];
            acc.x += wj * hv.x;
            acc.y += wj * hv.y;
        }
    }
    float2 b = bias2[lane];
    float o0 = acc.x + b.x, o1 = acc.y + b.y;
    if (do_relu) { o0 = fmaxf(o0, 0.f); o1 = fmaxf(o1, 0.f); }
    xout[(size_t)d * 64 + lane] = make_float2(o0, o1);
}

// ---------------- global mean pool (batch is sorted) ----------------
__global__ void k_pool(const float* __restrict__ x, const int* __restrict__ batch,
                       float* __restrict__ out) {
    __shared__ int sh[2];
    int g = blockIdx.x;
    int t = threadIdx.x;   // 128 threads = dims
    if (t == 0) {
        int lo = 0, hi = N_NODES;
        while (lo < hi) { int mid = (lo + hi) >> 1; if (batch[mid] < g) lo = mid + 1; else hi = mid; }
        sh[0] = lo;
        int lo2 = lo, hi2 = N_NODES;
        while (lo2 < hi2) { int mid = (lo2 + hi2) >> 1; if (batch[mid] < g + 1) lo2 = mid + 1; else hi2 = mid; }
        sh[1] = lo2;
    }
    __syncthreads();
    int lo = sh[0], hi = sh[1];
    float sum = 0.f;
    for (int i = lo; i < hi; i++) sum += x[(size_t)i * 128 + t];
    int cnt = hi - lo;
    out[g * 128 + t] = sum * (cnt > 0 ? 1.f / (float)cnt : 1.f);
}

extern "C" void kernel_launch(void* const* d_in, const int* in_sizes, int n_in,
                              void* d_out, int out_size, void* d_ws, size_t ws_size,
                              hipStream_t stream) {
    const int*   node_ids   = (const int*)d_in[0];
    const int*   edge_index = (const int*)d_in[1];   // [2][800000]
    const int*   batch      = (const int*)d_in[2];
    const float* emb        = (const float*)d_in[3];
    const float* W[3]  = {(const float*)d_in[4],  (const float*)d_in[8],  (const float*)d_in[12]};
    const float* As[3] = {(const float*)d_in[5],  (const float*)d_in[9],  (const float*)d_in[13]};
    const float* Ad[3] = {(const float*)d_in[6],  (const float*)d_in[10], (const float*)d_in[14]};
    const float* Bs[3] = {(const float*)d_in[7],  (const float*)d_in[11], (const float*)d_in[15]};

    char* ws = (char*)d_ws;
    size_t off = 0;
    auto alloc = [&](size_t bytes) {
        void* p = ws + off; off += (bytes + 255) & ~(size_t)255; return p;
    };
    float* xA      = (float*)alloc((size_t)N_NODES * 128 * 4);  // current x
    float* xB      = (float*)alloc((size_t)N_NODES * 128 * 4);  // h
    float* as_     = (float*)alloc((size_t)N_NODES * 4);
    float* ad_     = (float*)alloc((size_t)N_NODES * 4);
    int*   counts  = (int*)alloc((size_t)N_NODES * 4);
    int*   fill    = (int*)alloc((size_t)N_NODES * 4);
    int*   row_ptr = (int*)alloc((size_t)(N_NODES + 1) * 4);
    int*   blksum  = (int*)alloc(256 * 4);
    int*   srcs    = (int*)alloc((size_t)N_EDGES * 4);
    (void)ws_size; (void)in_sizes; (void)n_in; (void)out_size;

    hipMemsetAsync(counts, 0, (size_t)N_NODES * 4, stream);
    hipMemsetAsync(fill,   0, (size_t)N_NODES * 4, stream);

    // CSR by dst (shared by all 3 layers)
    int ebl = (N_EDGES + 255) / 256;
    int nb  = (N_NODES + 255) / 256;   // 196
    k_hist   <<<ebl, 256, 0, stream>>>(edge_index, counts);
    k_scan1  <<<nb, 256, 0, stream>>>(counts, row_ptr, blksum);
    k_scan2  <<<1, 256, 0, stream>>>(blksum, row_ptr, nb);
    k_scan3  <<<nb, 256, 0, stream>>>(row_ptr, blksum);
    k_scatter<<<ebl, 256, 0, stream>>>(edge_index, row_ptr, fill, srcs);

    // x0 = emb[node_ids]
    k_gather<<<(N_NODES * 32 + 255) / 256, 256, 0, stream>>>(node_ids, (const float4*)emb, (float4*)xA);

    for (int l = 0; l < 3; l++) {
        k_gemm<<<(N_NODES + 63) / 64, 256, 0, stream>>>(xA, W[l], xB);
        k_scores<<<(N_NODES * 64) / 256, 256, 0, stream>>>((const float2*)xB,
                 (const float2*)As[l], (const float2*)Ad[l], as_, ad_);
        k_aggregate<<<(N_NODES * 64) / 256, 256, 0, stream>>>((const float2*)xB,
                 as_, ad_, row_ptr, srcs, (const float2*)Bs[l], (float2*)xA,
                 (l < 2) ? 1 : 0);
    }
    k_pool<<<N_GRAPHS, 128, 0, stream>>>(xA, batch, (float*)d_out);
}

// Round 3
// 482.430 us; speedup vs baseline: 1.1633x; 1.1633x over previous
//
#include <hip/hip_runtime.h>
#include <math.h>

#define N_NODES    50000
#define N_EDGES_IN 800000
#define N_EDGES    850000   // + self loops
#define N_GRAPHS   512
#define NEG_SLOPE  0.2f
#define EPS_F      1e-16f

// ---------------- embedding gather: x[n] = emb[ids[n]] ----------------
__global__ void k_gather(const int* __restrict__ ids, const float4* __restrict__ emb,
                         float4* __restrict__ x) {
    int tid = blockIdx.x * blockDim.x + threadIdx.x;   // N_NODES * 32
    if (tid >= N_NODES * 32) return;
    int n = tid >> 5, c = tid & 31;
    x[n * 32 + c] = emb[ids[n] * 32 + c];
}

// ---------------- GEMM: h[N,128] = x[N,128] @ W[128,128] + fused scores -----
// block = 256 threads, 64 rows per block, full 128 cols.
// thread t: rows (t>>5)*8 .. +7, cols (t&31)*4 .. +3  (8x4 accumulator)
// epilogue additionally computes as_[r] = h[r]·a_src, ad_[r] = h[r]·a_dst
__global__ __launch_bounds__(256) void k_gemm(const float* __restrict__ x,
                                              const float* __restrict__ W,
                                              const float* __restrict__ a_s,
                                              const float* __restrict__ a_d,
                                              float* __restrict__ h,
                                              float* __restrict__ as_,
                                              float* __restrict__ ad_) {
    __shared__ float Ws[64 * 128];   // 32 KB  (one K-half)
    __shared__ float Xs[64 * 64];    // 16 KB
    int t = threadIdx.x;
    int row0 = blockIdx.x * 64;
    int g  = t >> 5;          // 0..7 row group
    int c4 = (t & 31) * 4;    // col start
    float acc[8][4] = {};
    for (int kc = 0; kc < 2; kc++) {
        // stage W rows [kc*64, kc*64+64) x 128  (2048 float4, 8/thread)
        {
            const float4* Wg = (const float4*)(W + kc * 64 * 128);
            float4* Wsv = (float4*)Ws;
            #pragma unroll
            for (int i = 0; i < 8; i++) Wsv[t + i * 256] = Wg[t + i * 256];
        }
        // stage X rows [row0, row0+64) cols [kc*64, +64)  (1024 float4, 4/thread)
        {
            float4* Xsv = (float4*)Xs;
            #pragma unroll
            for (int i = 0; i < 4; i++) {
                int j = t + i * 256;
                int r = j >> 4, cf = j & 15;
                int gr = row0 + r; if (gr >= N_NODES) gr = N_NODES - 1;
                Xsv[j] = ((const float4*)(x + (size_t)gr * 128 + kc * 64))[cf];
            }
        }
        __syncthreads();
        #pragma unroll 4
        for (int k = 0; k < 64; k++) {
            float4 wv = *(const float4*)&Ws[k * 128 + c4];
            #pragma unroll
            for (int i = 0; i < 8; i++) {
                float xv = Xs[(g * 8 + i) * 64 + k];
                acc[i][0] += xv * wv.x;
                acc[i][1] += xv * wv.y;
                acc[i][2] += xv * wv.z;
                acc[i][3] += xv * wv.w;
            }
        }
        __syncthreads();
    }
    #pragma unroll
    for (int i = 0; i < 8; i++) {
        int r = row0 + g * 8 + i;
        if (r < N_NODES)
            *(float4*)&h[(size_t)r * 128 + c4] =
                make_float4(acc[i][0], acc[i][1], acc[i][2], acc[i][3]);
    }
    // fused scores: reduce acc·a over the 32 threads of each row group.
    // threads of one row group are a 32-aligned lane span; xor offsets <32 stay inside.
    float4 sa = *(const float4*)&a_s[c4];
    float4 da = *(const float4*)&a_d[c4];
    #pragma unroll
    for (int i = 0; i < 8; i++) {
        float ps = acc[i][0]*sa.x + acc[i][1]*sa.y + acc[i][2]*sa.z + acc[i][3]*sa.w;
        float pd = acc[i][0]*da.x + acc[i][1]*da.y + acc[i][2]*da.z + acc[i][3]*da.w;
        #pragma unroll
        for (int off = 16; off; off >>= 1) {
            ps += __shfl_xor(ps, off, 64);
            pd += __shfl_xor(pd, off, 64);
        }
        if ((t & 31) == 0) {
            int r = row0 + g * 8 + i;
            if (r < N_NODES) { as_[r] = ps; ad_[r] = pd; }
        }
    }
}

// ---------------- CSR build by dst ----------------
__global__ void k_hist(const int* __restrict__ ei, int* __restrict__ counts) {
    int e = blockIdx.x * blockDim.x + threadIdx.x;
    if (e >= N_EDGES) return;
    int d = (e < N_EDGES_IN) ? ei[N_EDGES_IN + e] : (e - N_EDGES_IN);
    atomicAdd(&counts[d], 1);
}

__global__ void k_scan1(const int* __restrict__ counts, int* __restrict__ row_ptr,
                        int* __restrict__ blksum) {
    __shared__ int s[256];
    int t = threadIdx.x, i = blockIdx.x * 256 + t;
    int v = (i < N_NODES) ? counts[i] : 0;
    s[t] = v; __syncthreads();
    for (int off = 1; off < 256; off <<= 1) {
        int x = (t >= off) ? s[t - off] : 0;
        __syncthreads(); s[t] += x; __syncthreads();
    }
    if (i < N_NODES) row_ptr[i] = s[t] - v;           // block-local exclusive
    if (t == 255) blksum[blockIdx.x] = s[255];
}

__global__ void k_scan2(int* __restrict__ blksum, int* __restrict__ row_ptr, int nb) {
    __shared__ int s[256];
    int t = threadIdx.x;
    int v = (t < nb) ? blksum[t] : 0;
    s[t] = v; __syncthreads();
    for (int off = 1; off < 256; off <<= 1) {
        int x = (t >= off) ? s[t - off] : 0;
        __syncthreads(); s[t] += x; __syncthreads();
    }
    if (t < nb) blksum[t] = s[t] - v;                 // exclusive block offsets
    if (t == 0) row_ptr[N_NODES] = N_EDGES;           // total is a compile-time constant
}

__global__ void k_scan3(int* __restrict__ row_ptr, const int* __restrict__ blksum) {
    int i = blockIdx.x * 256 + threadIdx.x;
    if (i < N_NODES) row_ptr[i] += blksum[blockIdx.x];
}

__global__ void k_scatter(const int* __restrict__ ei, const int* __restrict__ row_ptr,
                          int* __restrict__ fill, int* __restrict__ srcs) {
    int e = blockIdx.x * blockDim.x + threadIdx.x;
    if (e >= N_EDGES) return;
    int s, d;
    if (e < N_EDGES_IN) { s = ei[e]; d = ei[N_EDGES_IN + e]; }
    else                { s = e - N_EDGES_IN; d = s; }
    int pos = row_ptr[d] + atomicAdd(&fill[d], 1);
    srcs[pos] = s;
}

// ---------------- softmax + weighted aggregation, one wave per dst ----------
// Pass B: half-wave per edge, float4 per lane (4 dims), 8-edge unroll for MLP.
__global__ __launch_bounds__(256) void k_aggregate(
        const float4* __restrict__ h4, const float* __restrict__ as_,
        const float* __restrict__ ad_, const int* __restrict__ row_ptr,
        const int* __restrict__ srcs, const float4* __restrict__ bias4,
        float4* __restrict__ xout, int do_relu) {
    int d = (blockIdx.x * blockDim.x + threadIdx.x) >> 6;
    int lane = threadIdx.x & 63;
    if (d >= N_NODES) return;
    int lo = row_ptr[d], hi = row_ptr[d + 1];
    int deg = hi - lo;                     // >= 1 (self-loop)
    float add = ad_[d];

    // pass A: online softmax stats per lane, then wave merge.
    // save chunk-0 (e, sidx) in registers — covers all edges when deg <= 64.
    float eS = -1e30f; int sS = 0;
    float m_l = -1e30f, s_l = 0.f;
    for (int j0 = 0; j0 < deg; j0 += 64) {
        int j = j0 + lane;
        float e = -1e30f; int sidx = 0;
        if (j < deg) {
            sidx = srcs[lo + j];
            e = as_[sidx] + add;
            e = (e > 0.f) ? e : NEG_SLOPE * e;
            float nm = fmaxf(m_l, e);
            s_l = s_l * __expf(m_l - nm) + __expf(e - nm);
            m_l = nm;
        }
        if (j0 == 0) { eS = e; sS = sidx; }
    }
    float m = m_l, s = s_l;
    #pragma unroll
    for (int off = 32; off; off >>= 1) {
        float om = __shfl_xor(m, off, 64);
        float os = __shfl_xor(s, off, 64);
        float nm = fmaxf(m, om);            // finite-sentinel: no inf-inf NaN
        s = s * __expf(m - nm) + os * __expf(om - nm);
        m = nm;
    }
    float inv = 1.f / (s + EPS_F);

    // pass B
    int half = lane >> 5, li = lane & 31;
    float4 acc = make_float4(0.f, 0.f, 0.f, 0.f);
    for (int j0 = 0; j0 < deg; j0 += 64) {
        float w; int sidx;
        if (j0 == 0) {                       // reuse saved chunk-0 scores
            w = __expf(eS - m) * inv;        // invalid lanes: eS=-1e30 -> w=0
            sidx = sS;
        } else {
            int j = j0 + lane;
            sidx = 0; w = 0.f;
            if (j < deg) {
                int si = srcs[lo + j];
                float e = as_[si] + add;
                e = (e > 0.f) ? e : NEG_SLOPE * e;
                w = __expf(e - m) * inv;
                sidx = si;
            }
        }
        int cnt = min(64, deg - j0);
        int jj = 0;
        for (; jj + 8 <= cnt; jj += 8) {
            float w0 = __shfl(w, jj     + half, 64); int s0 = __shfl(sidx, jj     + half, 64);
            float w1 = __shfl(w, jj + 2 + half, 64); int s1 = __shfl(sidx, jj + 2 + half, 64);
            float w2 = __shfl(w, jj + 4 + half, 64); int s2 = __shfl(sidx, jj + 4 + half, 64);
            float w3 = __shfl(w, jj + 6 + half, 64); int s3 = __shfl(sidx, jj + 6 + half, 64);
            float4 h0 = h4[(size_t)s0 * 32 + li];
            float4 h1 = h4[(size_t)s1 * 32 + li];
            float4 h2 = h4[(size_t)s2 * 32 + li];
            float4 h3 = h4[(size_t)s3 * 32 + li];
            acc.x += w0*h0.x; acc.y += w0*h0.y; acc.z += w0*h0.z; acc.w += w0*h0.w;
            acc.x += w1*h1.x; acc.y += w1*h1.y; acc.z += w1*h1.z; acc.w += w1*h1.w;
            acc.x += w2*h2.x; acc.y += w2*h2.y; acc.z += w2*h2.z; acc.w += w2*h2.w;
            acc.x += w3*h3.x; acc.y += w3*h3.y; acc.z += w3*h3.z; acc.w += w3*h3.w;
        }
        for (; jj < cnt; jj += 2) {
            // lanes >= cnt hold w=0, sidx=0 -> safe even when jj+1 == cnt
            float w0 = __shfl(w, jj + half, 64); int s0 = __shfl(sidx, jj + half, 64);
            float4 h0 = h4[(size_t)s0 * 32 + li];
            acc.x += w0*h0.x; acc.y += w0*h0.y; acc.z += w0*h0.z; acc.w += w0*h0.w;
        }
    }
    // merge the two half-wave partial sums
    acc.x += __shfl_xor(acc.x, 32, 64);
    acc.y += __shfl_xor(acc.y, 32, 64);
    acc.z += __shfl_xor(acc.z, 32, 64);
    acc.w += __shfl_xor(acc.w, 32, 64);
    if (half == 0) {
        float4 b = bias4[li];
        float4 o = make_float4(acc.x + b.x, acc.y + b.y, acc.z + b.z, acc.w + b.w);
        if (do_relu) {
            o.x = fmaxf(o.x, 0.f); o.y = fmaxf(o.y, 0.f);
            o.z = fmaxf(o.z, 0.f); o.w = fmaxf(o.w, 0.f);
        }
        xout[(size_t)d * 32 + li] = o;
    }
}

// ---------------- global mean pool (batch is sorted) ----------------
__global__ __launch_bounds__(512) void k_pool(const float* __restrict__ x,
                                              const int* __restrict__ batch,
                                              float* __restrict__ out) {
    __shared__ float red[512];
    __shared__ int sh[2];
    int g = blockIdx.x;
    int t = threadIdx.x;   // 512 = 4 rows x 128 dims
    if (t == 0) {
        int lo = 0, hi = N_NODES;
        while (lo < hi) { int mid = (lo + hi) >> 1; if (batch[mid] < g) lo = mid + 1; else hi = mid; }
        sh[0] = lo;
        int lo2 = lo, hi2 = N_NODES;
        while (lo2 < hi2) { int mid = (lo2 + hi2) >> 1; if (batch[mid] < g + 1) lo2 = mid + 1; else hi2 = mid; }
        sh[1] = lo2;
    }
    __syncthreads();
    int lo = sh[0], hi = sh[1];
    int sub = t >> 7, dim = t & 127;
    float sum = 0.f;
    for (int i = lo + sub; i < hi; i += 4) sum += x[(size_t)i * 128 + dim];
    red[t] = sum;
    __syncthreads();
    if (t < 128) {
        float s = red[t] + red[t + 128] + red[t + 256] + red[t + 384];
        int cnt = hi - lo;
        out[g * 128 + t] = s * (cnt > 0 ? 1.f / (float)cnt : 1.f);
    }
}

extern "C" void kernel_launch(void* const* d_in, const int* in_sizes, int n_in,
                              void* d_out, int out_size, void* d_ws, size_t ws_size,
                              hipStream_t stream) {
    const int*   node_ids   = (const int*)d_in[0];
    const int*   edge_index = (const int*)d_in[1];   // [2][800000]
    const int*   batch      = (const int*)d_in[2];
    const float* emb        = (const float*)d_in[3];
    const float* W[3]  = {(const float*)d_in[4],  (const float*)d_in[8],  (const float*)d_in[12]};
    const float* As[3] = {(const float*)d_in[5],  (const float*)d_in[9],  (const float*)d_in[13]};
    const float* Ad[3] = {(const float*)d_in[6],  (const float*)d_in[10], (const float*)d_in[14]};
    const float* Bs[3] = {(const float*)d_in[7],  (const float*)d_in[11], (const float*)d_in[15]};

    char* ws = (char*)d_ws;
    size_t off = 0;
    auto alloc = [&](size_t bytes) {
        void* p = ws + off; off += (bytes + 255) & ~(size_t)255; return p;
    };
    float* xA      = (float*)alloc((size_t)N_NODES * 128 * 4);  // current x
    float* xB      = (float*)alloc((size_t)N_NODES * 128 * 4);  // h
    float* as_     = (float*)alloc((size_t)N_NODES * 4);
    float* ad_     = (float*)alloc((size_t)N_NODES * 4);
    int*   counts  = (int*)alloc((size_t)N_NODES * 4);
    int*   fill    = (int*)alloc((size_t)N_NODES * 4);
    int*   row_ptr = (int*)alloc((size_t)(N_NODES + 1) * 4);
    int*   blksum  = (int*)alloc(256 * 4);
    int*   srcs    = (int*)alloc((size_t)N_EDGES * 4);
    (void)ws_size; (void)in_sizes; (void)n_in; (void)out_size;

    hipMemsetAsync(counts, 0, (size_t)N_NODES * 4, stream);
    hipMemsetAsync(fill,   0, (size_t)N_NODES * 4, stream);

    // CSR by dst (shared by all 3 layers)
    int ebl = (N_EDGES + 255) / 256;
    int nb  = (N_NODES + 255) / 256;   // 196
    k_hist   <<<ebl, 256, 0, stream>>>(edge_index, counts);
    k_scan1  <<<nb, 256, 0, stream>>>(counts, row_ptr, blksum);
    k_scan2  <<<1, 256, 0, stream>>>(blksum, row_ptr, nb);
    k_scan3  <<<nb, 256, 0, stream>>>(row_ptr, blksum);
    k_scatter<<<ebl, 256, 0, stream>>>(edge_index, row_ptr, fill, srcs);

    // x0 = emb[node_ids]
    k_gather<<<(N_NODES * 32 + 255) / 256, 256, 0, stream>>>(node_ids, (const float4*)emb, (float4*)xA);

    for (int l = 0; l < 3; l++) {
        k_gemm<<<(N_NODES + 63) / 64, 256, 0, stream>>>(xA, W[l], As[l], Ad[l], xB, as_, ad_);
        k_aggregate<<<(N_NODES * 64) / 256, 256, 0, stream>>>((const float4*)xB,
                 as_, ad_, row_ptr, srcs, (const float4*)Bs[l], (float4*)xA,
                 (l < 2) ? 1 : 0);
    }
    k_pool<<<N_GRAPHS, 512, 0, stream>>>(xA, batch, (float*)d_out);
}